// Round 3
// baseline (200.520 us; speedup 1.0000x reference)
//
#include <hip/hip_runtime.h>
#include <hip/hip_bf16.h>

#define BB 16
#define TT 64
#define SS 256
#define DD 512

typedef __bf16 bf16x8 __attribute__((ext_vector_type(8)));
typedef float f32x4 __attribute__((ext_vector_type(4)));

__device__ __forceinline__ ushort f2b(float x) {
    __hip_bfloat16 h = __float2bfloat16(x);
    return __builtin_bit_cast(ushort, h);
}

// ---------------- fp32 -> bf16 cast of the 5 GEMM operands, one launch ----------
#define S_SRC (BB * TT * DD)   // 524288
#define S_MB  (BB * SS * DD)   // 2097152
#define S_WQ  (DD * DD)        // 262144
#define S_WC  (DD * DD)        // 262144
#define S_WO  (DD * 2 * DD)    // 524288

__global__ __launch_bounds__(256) void cast_all(
    const float* __restrict__ src, const float* __restrict__ mb,
    const float* __restrict__ wq, const float* __restrict__ wc,
    const float* __restrict__ wo,
    ushort* __restrict__ src_b, ushort* __restrict__ mb_b,
    ushort* __restrict__ wq_b, ushort* __restrict__ wc_b,
    ushort* __restrict__ wo_b) {
    int g = blockIdx.x * 256 + threadIdx.x;  // float4-group index
    const int G0 = S_SRC / 4, G1 = S_MB / 4, G2 = S_WQ / 4, G3 = S_WC / 4;
    const float* in;
    ushort* out;
    int local;
    if (g < G0) { in = src; out = src_b; local = g; }
    else if (g < G0 + G1) { in = mb; out = mb_b; local = g - G0; }
    else if (g < G0 + G1 + G2) { in = wq; out = wq_b; local = g - G0 - G1; }
    else if (g < G0 + G1 + G2 + G3) { in = wc; out = wc_b; local = g - G0 - G1 - G2; }
    else { in = wo; out = wo_b; local = g - G0 - G1 - G2 - G3; }
    float4 x = *(const float4*)(in + (size_t)local * 4);
    ushort4 y = {f2b(x.x), f2b(x.y), f2b(x.z), f2b(x.w)};
    *(ushort4*)(out + (size_t)local * 4) = y;
}

// ---------------- LDS-free MFMA GEMM: C[m,n] = sum_k A[m,k]*Bm[n,k] (+bias) -----
// Block 256 thr = 4 waves; block tile 32x64; wave tile 16x32 (2 MFMA 16x16x32).
// Register-double-buffered fragment prefetch (3 loads in flight min; unroll 4
// lets the compiler keep ~12). TRANS: row m=b*TT+t stored at ((t*BB)+b)*N+n.
// BATCH_A: A and C z-batched (A by M*K, C by M*N).
template <int K, int HAS_BIAS, int TRANS, int BATCH_A>
__global__ __launch_bounds__(256) void gemm_mfma(const ushort* __restrict__ A,
                                                 const ushort* __restrict__ Bm,
                                                 const float* __restrict__ bias,
                                                 float* __restrict__ C,
                                                 int M, int N) {
    const int tid = threadIdx.x;
    const int lane = tid & 63;
    const int wave = tid >> 6;
    const int wm = wave & 1, wn = wave >> 1;
    const int m0 = blockIdx.y * 32 + wm * 16;
    const int n0 = blockIdx.x * 64 + wn * 32;
    if (BATCH_A) {
        A += (size_t)blockIdx.z * (size_t)M * K;
        C += (size_t)blockIdx.z * (size_t)M * N;
    }
    const int l15 = lane & 15;
    const int kg = (lane >> 4) * 8;  // A[m=lane&15][k=quad*8+j]
    const ushort* Ap = A + (size_t)(m0 + l15) * K + kg;
    const ushort* Bp0 = Bm + (size_t)(n0 + l15) * K + kg;
    const ushort* Bp1 = Bp0 + (size_t)16 * K;
    f32x4 acc0 = {0.f, 0.f, 0.f, 0.f}, acc1 = {0.f, 0.f, 0.f, 0.f};
    bf16x8 a = *(const bf16x8*)Ap;
    bf16x8 b0 = *(const bf16x8*)Bp0;
    bf16x8 b1 = *(const bf16x8*)Bp1;
#pragma unroll 4
    for (int k0 = 32; k0 < K; k0 += 32) {
        bf16x8 an = *(const bf16x8*)(Ap + k0);
        bf16x8 b0n = *(const bf16x8*)(Bp0 + k0);
        bf16x8 b1n = *(const bf16x8*)(Bp1 + k0);
        acc0 = __builtin_amdgcn_mfma_f32_16x16x32_bf16(a, b0, acc0, 0, 0, 0);
        acc1 = __builtin_amdgcn_mfma_f32_16x16x32_bf16(a, b1, acc1, 0, 0, 0);
        a = an; b0 = b0n; b1 = b1n;
    }
    acc0 = __builtin_amdgcn_mfma_f32_16x16x32_bf16(a, b0, acc0, 0, 0, 0);
    acc1 = __builtin_amdgcn_mfma_f32_16x16x32_bf16(a, b1, acc1, 0, 0, 0);
    // C/D layout: col = lane&15, row = (lane>>4)*4 + reg
#pragma unroll
    for (int r = 0; r < 4; ++r) {
        int m = m0 + (lane >> 4) * 4 + r;
        int n = n0 + l15;
        float v0 = acc0[r], v1 = acc1[r];
        if (HAS_BIAS) { v0 += bias[n]; v1 += bias[n + 16]; }
        size_t i0, i1;
        if (TRANS) {
            int bb = m >> 6, t = m & 63;  // m = b*64 + t
            size_t row = ((size_t)t * BB + bb) * N;
            i0 = row + n; i1 = row + n + 16;
        } else {
            i0 = (size_t)m * N + n; i1 = i0 + 16;
        }
        C[i0] = v0; C[i1] = v1;
    }
}

// ---------------- fused align + sparsemax + context + concat --------------------
// One block per (b,t); thread tid owns score s=tid. uh is natural (B,S,D) fp32:
// thread reads its private 2KB row via float4 (4x fewer loads, full-line L1 use);
// wq row and v are wave-uniform -> s_load.
__global__ __launch_bounds__(256) void align3(const float* __restrict__ wq,
                                              const float* __restrict__ uh,
                                              const float* __restrict__ mb,
                                              const int* __restrict__ mask,
                                              const float* __restrict__ v,
                                              const float* __restrict__ src,
                                              float* __restrict__ align_out,
                                              ushort* __restrict__ concat) {
    const int bt = blockIdx.x;
    const int b = bt >> 6, t = bt & 63;
    const int tid = threadIdx.x;
    const int lane = tid & 63;
    const int wave = tid >> 6;
    __shared__ float zs[SS];

    const float* wrow = wq + (size_t)bt * DD;  // wave-uniform
    const float4* u4 = (const float4*)(uh + ((size_t)b * SS + tid) * DD);
    float p = 0.f;
#pragma unroll 8
    for (int j = 0; j < DD / 4; ++j) {
        float4 u = u4[j];
        float uu[4] = {u.x, u.y, u.z, u.w};
#pragma unroll
        for (int q = 0; q < 4; ++q) {
            int d = j * 4 + q;
            float s = wrow[d] + uu[q];
            float e = __expf(2.0f * s);
            float r = __builtin_amdgcn_rcpf(e + 1.0f);
            float th = __builtin_fmaf(-2.0f, r, 1.0f);  // tanh = 1 - 2/(e^2x+1)
            p = __builtin_fmaf(v[d], th, p);
        }
    }
    zs[tid] = (mask[b * SS + tid] != 0) ? p : -1e9f;
    __syncthreads();

    // Sparsemax over 256 scores: wave 0 only (shuffle-only, no barriers).
    if (wave == 0) {
        float z0 = zs[lane];
        float z1 = zs[lane + 64];
        float z2 = zs[lane + 128];
        float z3 = zs[lane + 192];
        float mx = fmaxf(fmaxf(z0, z1), fmaxf(z2, z3));
#pragma unroll
        for (int off = 32; off > 0; off >>= 1) mx = fmaxf(mx, __shfl_xor(mx, off, 64));
        z0 -= mx; z1 -= mx; z2 -= mx; z3 -= mx;
        // Solve sum_i relu(z_i - tau) = 1, tau in [-1, 0], by bisection.
        float lo = -1.0f, hi = 0.0f;
        for (int it = 0; it < 24; ++it) {
            float mid = 0.5f * (lo + hi);
            float ssum = fmaxf(z0 - mid, 0.f) + fmaxf(z1 - mid, 0.f) +
                         fmaxf(z2 - mid, 0.f) + fmaxf(z3 - mid, 0.f);
#pragma unroll
            for (int off = 32; off > 0; off >>= 1) ssum += __shfl_xor(ssum, off, 64);
            if (ssum >= 1.0f) lo = mid; else hi = mid;
        }
        float tau = 0.5f * (lo + hi);
        zs[lane] = fmaxf(z0 - tau, 0.f);
        zs[lane + 64] = fmaxf(z1 - tau, 0.f);
        zs[lane + 128] = fmaxf(z2 - tau, 0.f);
        zs[lane + 192] = fmaxf(z3 - tau, 0.f);
    }
    __syncthreads();

    align_out[((size_t)t * BB + b) * SS + tid] = zs[tid];

    // c[d] = sum_s p[s] * mb[b,s,d]; thread owns d = tid, tid+256.
    const float* mbb = mb + (size_t)b * SS * DD;
    float acc0 = 0.f, acc1 = 0.f;
    for (int s = 0; s < SS; ++s) {
        float ps = zs[s];
        if (ps > 0.f) {
            acc0 += ps * mbb[(size_t)s * DD + tid];
            acc1 += ps * mbb[(size_t)s * DD + 256 + tid];
        }
    }
    ushort* crow = concat + (size_t)bt * (2 * DD);
    crow[tid] = f2b(acc0);
    crow[tid + 256] = f2b(acc1);
    const float* srow = src + (size_t)bt * DD;
    crow[DD + tid] = f2b(srow[tid]);
    crow[DD + 256 + tid] = f2b(srow[tid + 256]);
}

extern "C" void kernel_launch(void* const* d_in, const int* in_sizes, int n_in,
                              void* d_out, int out_size, void* d_ws, size_t ws_size,
                              hipStream_t stream) {
    const float* source = (const float*)d_in[0];       // (B,T,D)
    const float* memory_bank = (const float*)d_in[1];  // (B,S,D)
    const int* memory_mask = (const int*)d_in[2];      // (B,S)
    const float* W_q = (const float*)d_in[3];          // (D,D)
    const float* b_q = (const float*)d_in[4];          // (D,)
    const float* W_c = (const float*)d_in[5];          // (D,D)
    const float* v = (const float*)d_in[6];            // (D,)
    const float* W_out = (const float*)d_in[7];        // (D,2D)
    const float* b_out = (const float*)d_in[8];        // (D,)

    float* out0 = (float*)d_out;                   // attn_h (T,B,D)
    float* out1 = out0 + (size_t)TT * BB * DD;     // align_vectors (T,B,S)

    // workspace layout (all 16B-aligned; ~19 MB total)
    float* wq_f = (float*)d_ws;                    // (B*T, D) fp32      2 MB
    float* uh = wq_f + S_SRC;                      // (B, S, D) fp32     8 MB
    ushort* src_b = (ushort*)(uh + S_MB);          // 1 MB
    ushort* mb_b = src_b + S_SRC;                  // 4 MB
    ushort* wqw_b = mb_b + S_MB;                   // 0.5 MB
    ushort* wcw_b = wqw_b + S_WQ;                  // 0.5 MB
    ushort* wo_b = wcw_b + S_WC;                   // 1 MB
    ushort* cc_b = wo_b + S_WO;                    // (B*T, 2D) bf16     2 MB

    dim3 blk(256);
    // 1. cast the 5 bf16 operands
    int ngroups = (S_SRC + S_MB + S_WQ + S_WC + S_WO) / 4;
    cast_all<<<dim3(ngroups / 256), blk, 0, stream>>>(
        source, memory_bank, W_q, W_c, W_out, src_b, mb_b, wqw_b, wcw_b, wo_b);
    // 2. wq = source @ W_q^T + b_q            (M=1024, N=512, K=512)
    gemm_mfma<DD, 1, 0, 0><<<dim3(DD / 64, BB * TT / 32), blk, 0, stream>>>(
        src_b, wqw_b, b_q, wq_f, BB * TT, DD);
    // 3. uh[b] = mb[b] @ W_c^T  (natural (B,S,D) layout; M=256, N=512, K=512, batch B)
    gemm_mfma<DD, 0, 0, 1><<<dim3(DD / 64, SS / 32, BB), blk, 0, stream>>>(
        mb_b, wcw_b, nullptr, uh, SS, DD);
    // 4. fused align + sparsemax + context + concat
    align3<<<dim3(BB * TT), blk, 0, stream>>>(
        wq_f, uh, memory_bank, memory_mask, v, source, out1, cc_b);
    // 5. attn_h = concat @ W_out^T + b_out, stored (T,B,D)   (M=1024, N=512, K=1024)
    gemm_mfma<2 * DD, 1, 1, 0><<<dim3(DD / 64, BB * TT / 32), blk, 0, stream>>>(
        cc_b, wo_b, b_out, out0, BB * TT, DD);
}

// Round 4
// 177.882 us; speedup vs baseline: 1.1273x; 1.1273x over previous
//
#include <hip/hip_runtime.h>
#include <hip/hip_bf16.h>

#define BB 16
#define TT 64
#define SS 256
#define DD 512

typedef __bf16 bf16x8 __attribute__((ext_vector_type(8)));
typedef float f32x4 __attribute__((ext_vector_type(4)));

__device__ __forceinline__ ushort f2b(float x) {
    __hip_bfloat16 h = __float2bfloat16(x);
    return __builtin_bit_cast(ushort, h);
}

// ---------------- fp32 -> bf16 cast of the 5 GEMM operands, one launch ----------
#define S_SRC (BB * TT * DD)   // 524288
#define S_MB  (BB * SS * DD)   // 2097152
#define S_WQ  (DD * DD)        // 262144
#define S_WC  (DD * DD)        // 262144
#define S_WO  (DD * 2 * DD)    // 524288

__global__ __launch_bounds__(256) void cast_all(
    const float* __restrict__ src, const float* __restrict__ mb,
    const float* __restrict__ wq, const float* __restrict__ wc,
    const float* __restrict__ wo,
    ushort* __restrict__ src_b, ushort* __restrict__ mb_b,
    ushort* __restrict__ wq_b, ushort* __restrict__ wc_b,
    ushort* __restrict__ wo_b) {
    int g = blockIdx.x * 256 + threadIdx.x;  // float4-group index
    const int G0 = S_SRC / 4, G1 = S_MB / 4, G2 = S_WQ / 4, G3 = S_WC / 4;
    const float* in;
    ushort* out;
    int local;
    if (g < G0) { in = src; out = src_b; local = g; }
    else if (g < G0 + G1) { in = mb; out = mb_b; local = g - G0; }
    else if (g < G0 + G1 + G2) { in = wq; out = wq_b; local = g - G0 - G1; }
    else if (g < G0 + G1 + G2 + G3) { in = wc; out = wc_b; local = g - G0 - G1 - G2; }
    else { in = wo; out = wo_b; local = g - G0 - G1 - G2 - G3; }
    float4 x = *(const float4*)(in + (size_t)local * 4);
    ushort4 y = {f2b(x.x), f2b(x.y), f2b(x.z), f2b(x.w)};
    *(ushort4*)(out + (size_t)local * 4) = y;
}

// ---------------- LDS-free MFMA GEMM: C[m,n] = sum_k A[m,k]*Bm[n,k] (+bias) -----
// Block 256 thr = 4 waves; block tile 32x32; wave tile 16x16 (1 MFMA 16x16x32,
// 2 fragment loads / 32-k). Small-matrix regime: maximize block count for
// latency hiding, fragments straight from L2. Register-double-buffer prefetch.
// TRANS: row m=b*TT+t stored at ((t*BB)+b)*N+n.  BATCH: Bm,C z-batched.
// EXP2X: store exp(2*val) (for the tanh factorization in align4).
template <int K, int HAS_BIAS, int TRANS, int BATCH, int EXP2X>
__global__ __launch_bounds__(256) void gemm16(const ushort* __restrict__ A,
                                              const ushort* __restrict__ Bm,
                                              const float* __restrict__ bias,
                                              float* __restrict__ C,
                                              int M, int N) {
    const int tid = threadIdx.x;
    const int lane = tid & 63;
    const int wave = tid >> 6;
    const int m0 = blockIdx.y * 32 + (wave & 1) * 16;
    const int n0 = blockIdx.x * 32 + (wave >> 1) * 16;
    if (BATCH) {
        Bm += (size_t)blockIdx.z * (size_t)N * K;
        C += (size_t)blockIdx.z * (size_t)M * N;
    }
    const int l15 = lane & 15;
    const int kg = (lane >> 4) * 8;  // A[m=lane&15][k=quad*8+j]
    const ushort* Ap = A + (size_t)(m0 + l15) * K + kg;
    const ushort* Bp = Bm + (size_t)(n0 + l15) * K + kg;
    f32x4 acc = {0.f, 0.f, 0.f, 0.f};
    bf16x8 a = *(const bf16x8*)Ap;
    bf16x8 b = *(const bf16x8*)Bp;
#pragma unroll 8
    for (int k0 = 32; k0 < K; k0 += 32) {
        bf16x8 an = *(const bf16x8*)(Ap + k0);
        bf16x8 bn = *(const bf16x8*)(Bp + k0);
        acc = __builtin_amdgcn_mfma_f32_16x16x32_bf16(a, b, acc, 0, 0, 0);
        a = an; b = bn;
    }
    acc = __builtin_amdgcn_mfma_f32_16x16x32_bf16(a, b, acc, 0, 0, 0);
    // C/D layout: col = lane&15, row = (lane>>4)*4 + reg
#pragma unroll
    for (int r = 0; r < 4; ++r) {
        int m = m0 + (lane >> 4) * 4 + r;
        int n = n0 + l15;
        float val = acc[r];
        if (HAS_BIAS) val += bias[n];
        if (EXP2X) val = __expf(2.0f * val);
        size_t idx;
        if (TRANS) {
            int bb = m >> 6, t = m & 63;  // m = b*64 + t
            idx = ((size_t)t * BB + bb) * N + n;
        } else {
            idx = (size_t)m * N + n;
        }
        C[idx] = val;
    }
}

// ---------------- fused align + sparsemax + context + concat --------------------
// Grid (32 tgroups, 16 b); block handles t0=2*tg, t1=t0+1. Thread tid owns s=tid.
// Uses sum_d v_d tanh(w+u) = sumv - 2*sum_d v_d/(E_d*U_sd + 1), with
// E = exp(2 wq) (per-row, wave-uniform s_loads) and U = exp(2 uh) in (B,D,S)
// layout (wave-coalesced 256B loads, each load reused for both t rows).
__global__ __launch_bounds__(256) void align4(const float* __restrict__ Ewq,
                                              const float* __restrict__ EuT,
                                              const float* __restrict__ mb,
                                              const int* __restrict__ mask,
                                              const float* __restrict__ v,
                                              const float* __restrict__ src,
                                              float* __restrict__ align_out,
                                              ushort* __restrict__ concat) {
    const int tg = blockIdx.x, b = blockIdx.y;
    const int t0 = tg * 2, t1 = t0 + 1;
    const int bt0 = b * TT + t0, bt1 = bt0 + 1;
    const int tid = threadIdx.x;
    const int lane = tid & 63;
    const int wave = tid >> 6;
    __shared__ float zs0[SS], zs1[SS];

    // sumv = sum_d v[d], computed redundantly per wave (lane-parallel + shuffle)
    float sv = 0.f;
#pragma unroll
    for (int j = 0; j < 8; ++j) sv += v[lane + 64 * j];
#pragma unroll
    for (int off = 32; off > 0; off >>= 1) sv += __shfl_xor(sv, off, 64);

    const float* E0 = Ewq + (size_t)bt0 * DD;  // wave-uniform
    const float* E1 = Ewq + (size_t)bt1 * DD;
    const float* U = EuT + (size_t)b * DD * SS + tid;
    float a0 = 0.f, a1 = 0.f;
#pragma unroll 16
    for (int d = 0; d < DD; ++d) {
        float u = U[(size_t)d * SS];
        float den0 = __builtin_fmaf(E0[d], u, 1.0f);
        float den1 = __builtin_fmaf(E1[d], u, 1.0f);
        float r0 = __builtin_amdgcn_rcpf(den0);
        float r1 = __builtin_amdgcn_rcpf(den1);
        float vd = v[d];
        a0 = __builtin_fmaf(vd, r0, a0);
        a1 = __builtin_fmaf(vd, r1, a1);
    }
    int mk = mask[b * SS + tid];
    zs0[tid] = mk ? (sv - 2.0f * a0) : -1e9f;
    zs1[tid] = mk ? (sv - 2.0f * a1) : -1e9f;
    __syncthreads();

    // Sparsemax: wave 0 handles zs0, wave 1 handles zs1 (shuffle-only, no barrier)
    if (wave < 2) {
        float* zz = wave ? zs1 : zs0;
        float z0 = zz[lane];
        float z1 = zz[lane + 64];
        float z2 = zz[lane + 128];
        float z3 = zz[lane + 192];
        float mx = fmaxf(fmaxf(z0, z1), fmaxf(z2, z3));
#pragma unroll
        for (int off = 32; off > 0; off >>= 1) mx = fmaxf(mx, __shfl_xor(mx, off, 64));
        z0 -= mx; z1 -= mx; z2 -= mx; z3 -= mx;
        // Solve sum_i relu(z_i - tau) = 1, tau in [-1, 0], by bisection.
        float lo = -1.0f, hi = 0.0f;
        for (int it = 0; it < 24; ++it) {
            float mid = 0.5f * (lo + hi);
            float ssum = fmaxf(z0 - mid, 0.f) + fmaxf(z1 - mid, 0.f) +
                         fmaxf(z2 - mid, 0.f) + fmaxf(z3 - mid, 0.f);
#pragma unroll
            for (int off = 32; off > 0; off >>= 1) ssum += __shfl_xor(ssum, off, 64);
            if (ssum >= 1.0f) lo = mid; else hi = mid;
        }
        float tau = 0.5f * (lo + hi);
        zz[lane] = fmaxf(z0 - tau, 0.f);
        zz[lane + 64] = fmaxf(z1 - tau, 0.f);
        zz[lane + 128] = fmaxf(z2 - tau, 0.f);
        zz[lane + 192] = fmaxf(z3 - tau, 0.f);
    }
    __syncthreads();

    align_out[((size_t)t0 * BB + b) * SS + tid] = zs0[tid];
    align_out[((size_t)t1 * BB + b) * SS + tid] = zs1[tid];

    // c[t,d] = sum_s p[t,s] * mb[b,s,d]; thread owns d = tid, tid+256.
    const float* mbb = mb + (size_t)b * SS * DD;
    float c00 = 0.f, c01 = 0.f, c10 = 0.f, c11 = 0.f;
    for (int s = 0; s < SS; ++s) {
        float p0 = zs0[s], p1 = zs1[s];
        if (p0 > 0.f || p1 > 0.f) {  // block-uniform skip
            float m0v = mbb[(size_t)s * DD + tid];
            float m1v = mbb[(size_t)s * DD + 256 + tid];
            c00 += p0 * m0v; c01 += p0 * m1v;
            c10 += p1 * m0v; c11 += p1 * m1v;
        }
    }
    ushort* crow0 = concat + (size_t)bt0 * (2 * DD);
    ushort* crow1 = concat + (size_t)bt1 * (2 * DD);
    crow0[tid] = f2b(c00); crow0[tid + 256] = f2b(c01);
    crow1[tid] = f2b(c10); crow1[tid + 256] = f2b(c11);
    const float* srow0 = src + (size_t)bt0 * DD;
    const float* srow1 = src + (size_t)bt1 * DD;
    crow0[DD + tid] = f2b(srow0[tid]); crow0[DD + 256 + tid] = f2b(srow0[tid + 256]);
    crow1[DD + tid] = f2b(srow1[tid]); crow1[DD + 256 + tid] = f2b(srow1[tid + 256]);
}

extern "C" void kernel_launch(void* const* d_in, const int* in_sizes, int n_in,
                              void* d_out, int out_size, void* d_ws, size_t ws_size,
                              hipStream_t stream) {
    const float* source = (const float*)d_in[0];       // (B,T,D)
    const float* memory_bank = (const float*)d_in[1];  // (B,S,D)
    const int* memory_mask = (const int*)d_in[2];      // (B,S)
    const float* W_q = (const float*)d_in[3];          // (D,D)
    const float* b_q = (const float*)d_in[4];          // (D,)
    const float* W_c = (const float*)d_in[5];          // (D,D)
    const float* v = (const float*)d_in[6];            // (D,)
    const float* W_out = (const float*)d_in[7];        // (D,2D)
    const float* b_out = (const float*)d_in[8];        // (D,)

    float* out0 = (float*)d_out;                   // attn_h (T,B,D)
    float* out1 = out0 + (size_t)TT * BB * DD;     // align_vectors (T,B,S)

    // workspace layout (~19 MB)
    float* Ewq = (float*)d_ws;                     // (B*T, D) fp32  exp(2wq)  2 MB
    float* EuT = Ewq + S_SRC;                      // (B, D, S) fp32 exp(2uh)  8 MB
    ushort* src_b = (ushort*)(EuT + S_MB);         // 1 MB
    ushort* mb_b = src_b + S_SRC;                  // 4 MB
    ushort* wqw_b = mb_b + S_MB;                   // 0.5 MB
    ushort* wcw_b = wqw_b + S_WQ;                  // 0.5 MB
    ushort* wo_b = wcw_b + S_WC;                   // 1 MB
    ushort* cc_b = wo_b + S_WO;                    // (B*T, 2D) bf16 2 MB

    dim3 blk(256);
    // 1. cast the 5 bf16 operands
    int ngroups = (S_SRC + S_MB + S_WQ + S_WC + S_WO) / 4;
    cast_all<<<dim3(ngroups / 256), blk, 0, stream>>>(
        source, memory_bank, W_q, W_c, W_out, src_b, mb_b, wqw_b, wcw_b, wo_b);
    // 2. Ewq = exp(2*(source @ W_q^T + b_q))     (M=1024, N=512, K=512)
    gemm16<DD, 1, 0, 0, 1><<<dim3(DD / 32, BB * TT / 32), blk, 0, stream>>>(
        src_b, wqw_b, b_q, Ewq, BB * TT, DD);
    // 3. EuT[b] = exp(2*(W_c @ mb[b]^T))         (M=512(d), N=256(s), K=512, batch 16)
    gemm16<DD, 0, 0, 1, 1><<<dim3(SS / 32, DD / 32, BB), blk, 0, stream>>>(
        wcw_b, mb_b, nullptr, EuT, DD, SS);
    // 4. fused align + sparsemax + context + concat (2 t-rows per block)
    align4<<<dim3(TT / 2, BB), blk, 0, stream>>>(
        Ewq, EuT, memory_bank, memory_mask, v, source, out1, cc_b);
    // 5. attn_h = concat @ W_out^T + b_out, stored (T,B,D)  (M=1024, N=512, K=1024)
    gemm16<2 * DD, 1, 1, 0, 0><<<dim3(DD / 32, BB * TT / 32), blk, 0, stream>>>(
        cc_b, wo_b, b_out, out0, BB * TT, DD);
}

// Round 5
// 138.075 us; speedup vs baseline: 1.4523x; 1.2883x over previous
//
#include <hip/hip_runtime.h>
#include <hip/hip_bf16.h>

#define BB 16
#define TT 64
#define SS 256
#define DD 512

typedef __bf16 bf16x8 __attribute__((ext_vector_type(8)));
typedef float f32x4 __attribute__((ext_vector_type(4)));

__device__ __forceinline__ ushort f2b(float x) {
    __hip_bfloat16 h = __float2bfloat16(x);
    return __builtin_bit_cast(ushort, h);
}
__device__ __forceinline__ float b2f(ushort u) {
    unsigned int x = (unsigned int)u << 16;
    return __builtin_bit_cast(float, x);
}

// ---------------- fp32 -> bf16 cast of the 5 GEMM operands, one launch ----------
#define S_SRC (BB * TT * DD)   // 524288
#define S_MB  (BB * SS * DD)   // 2097152
#define S_WQ  (DD * DD)        // 262144
#define S_WC  (DD * DD)        // 262144
#define S_WO  (DD * 2 * DD)    // 524288

__global__ __launch_bounds__(256) void cast_all(
    const float* __restrict__ src, const float* __restrict__ mb,
    const float* __restrict__ wq, const float* __restrict__ wc,
    const float* __restrict__ wo,
    ushort* __restrict__ src_b, ushort* __restrict__ mb_b,
    ushort* __restrict__ wq_b, ushort* __restrict__ wc_b,
    ushort* __restrict__ wo_b) {
    int g = blockIdx.x * 256 + threadIdx.x;  // float4-group index
    const int G0 = S_SRC / 4, G1 = S_MB / 4, G2 = S_WQ / 4, G3 = S_WC / 4;
    const float* in;
    ushort* out;
    int local;
    if (g < G0) { in = src; out = src_b; local = g; }
    else if (g < G0 + G1) { in = mb; out = mb_b; local = g - G0; }
    else if (g < G0 + G1 + G2) { in = wq; out = wq_b; local = g - G0 - G1; }
    else if (g < G0 + G1 + G2 + G3) { in = wc; out = wc_b; local = g - G0 - G1 - G2; }
    else { in = wo; out = wo_b; local = g - G0 - G1 - G2 - G3; }
    float4 x = *(const float4*)(in + (size_t)local * 4);
    ushort4 y = {f2b(x.x), f2b(x.y), f2b(x.z), f2b(x.w)};
    *(ushort4*)(out + (size_t)local * 4) = y;
}

// ---------------- LDS-staged MFMA GEMM: C[m,n] = sum_k A[m,k]*Bm[n,k] ----------
// 64x64 tile, BK=64, 256 thr = 4 waves, wave-tile 32x32 (2x2 MFMA 16x16x32).
// LDS rows padded to 72 bf16 (144 B): frag ds_read_b128 lands 2-way banks (free).
// Global prefetch for phase p+1 issued before compute(p).
// BATCH: 0 none, 1 A&C z-batched, 2 B&C z-batched. M,N,K multiples of 64.
template <int HAS_BIAS, int EXP2X, int OUT_BF16, int BATCH>
__global__ __launch_bounds__(256) void gemm_lds(const ushort* __restrict__ A,
                                                const ushort* __restrict__ Bm,
                                                const float* __restrict__ bias,
                                                void* __restrict__ Cout,
                                                int M, int N, int K,
                                                int lda, int ldb) {
    __shared__ ushort Asm[64 * 72];
    __shared__ ushort Bsm[64 * 72];
    const int tid = threadIdx.x;
    const int lane = tid & 63;
    const int wave = tid >> 6;
    const int wm = wave & 1, wn = wave >> 1;
    const int m0 = blockIdx.y * 64;
    const int n0 = blockIdx.x * 64;
    if (BATCH == 1) A += (size_t)blockIdx.z * (size_t)M * K;
    if (BATCH == 2) Bm += (size_t)blockIdx.z * (size_t)N * K;
    const size_t cbase = (BATCH != 0) ? (size_t)blockIdx.z * (size_t)M * N : 0;

    const int srow = tid >> 3;    // 0..31
    const int schunk = tid & 7;   // 8-bf16 chunk within the 64-k slice
    const ushort* Ag0 = A + (size_t)(m0 + srow) * lda + schunk * 8;
    const ushort* Ag1 = Ag0 + (size_t)32 * lda;
    const ushort* Bg0 = Bm + (size_t)(n0 + srow) * ldb + schunk * 8;
    const ushort* Bg1 = Bg0 + (size_t)32 * ldb;
    const int lw = srow * 72 + schunk * 8;

    const int l15 = lane & 15, quad = lane >> 4;
    const int ar = (wm * 32 + l15) * 72 + quad * 8;
    const int br = (wn * 32 + l15) * 72 + quad * 8;

    f32x4 acc00 = {0.f, 0.f, 0.f, 0.f}, acc01 = {0.f, 0.f, 0.f, 0.f};
    f32x4 acc10 = {0.f, 0.f, 0.f, 0.f}, acc11 = {0.f, 0.f, 0.f, 0.f};

    uint4 a0 = *(const uint4*)Ag0;
    uint4 a1 = *(const uint4*)Ag1;
    uint4 b0 = *(const uint4*)Bg0;
    uint4 b1 = *(const uint4*)Bg1;
    const int P = K >> 6;
    for (int p = 0; p < P; ++p) {
        __syncthreads();  // prior phase's ds_reads complete
        *(uint4*)&Asm[lw] = a0;
        *(uint4*)&Asm[lw + 32 * 72] = a1;
        *(uint4*)&Bsm[lw] = b0;
        *(uint4*)&Bsm[lw + 32 * 72] = b1;
        __syncthreads();
        if (p + 1 < P) {  // prefetch next slice, overlaps compute below
            int ko = (p + 1) << 6;
            a0 = *(const uint4*)(Ag0 + ko);
            a1 = *(const uint4*)(Ag1 + ko);
            b0 = *(const uint4*)(Bg0 + ko);
            b1 = *(const uint4*)(Bg1 + ko);
        }
        bf16x8 fa0 = *(const bf16x8*)&Asm[ar];
        bf16x8 fa1 = *(const bf16x8*)&Asm[ar + 16 * 72];
        bf16x8 fb0 = *(const bf16x8*)&Bsm[br];
        bf16x8 fb1 = *(const bf16x8*)&Bsm[br + 16 * 72];
        acc00 = __builtin_amdgcn_mfma_f32_16x16x32_bf16(fa0, fb0, acc00, 0, 0, 0);
        acc01 = __builtin_amdgcn_mfma_f32_16x16x32_bf16(fa0, fb1, acc01, 0, 0, 0);
        acc10 = __builtin_amdgcn_mfma_f32_16x16x32_bf16(fa1, fb0, acc10, 0, 0, 0);
        acc11 = __builtin_amdgcn_mfma_f32_16x16x32_bf16(fa1, fb1, acc11, 0, 0, 0);
        fa0 = *(const bf16x8*)&Asm[ar + 32];
        fa1 = *(const bf16x8*)&Asm[ar + 16 * 72 + 32];
        fb0 = *(const bf16x8*)&Bsm[br + 32];
        fb1 = *(const bf16x8*)&Bsm[br + 16 * 72 + 32];
        acc00 = __builtin_amdgcn_mfma_f32_16x16x32_bf16(fa0, fb0, acc00, 0, 0, 0);
        acc01 = __builtin_amdgcn_mfma_f32_16x16x32_bf16(fa0, fb1, acc01, 0, 0, 0);
        acc10 = __builtin_amdgcn_mfma_f32_16x16x32_bf16(fa1, fb0, acc10, 0, 0, 0);
        acc11 = __builtin_amdgcn_mfma_f32_16x16x32_bf16(fa1, fb1, acc11, 0, 0, 0);
    }
    // epilogue: C/D layout col=l15, row=quad*4+reg
    const int nA = n0 + wn * 32 + l15;
    float bias0 = 0.f, bias1 = 0.f;
    if (HAS_BIAS) { bias0 = bias[nA]; bias1 = bias[nA + 16]; }
    float* Cf = (float*)Cout;
    ushort* Cb = (ushort*)Cout;
#pragma unroll
    for (int mt = 0; mt < 2; ++mt) {
        f32x4 accN0 = mt ? acc10 : acc00;
        f32x4 accN1 = mt ? acc11 : acc01;
#pragma unroll
        for (int r = 0; r < 4; ++r) {
            int m = m0 + wm * 32 + mt * 16 + quad * 4 + r;
            float v0 = accN0[r] + bias0;
            float v1 = accN1[r] + bias1;
            if (EXP2X) { v0 = __expf(2.0f * v0); v1 = __expf(2.0f * v1); }
            size_t i0 = cbase + (size_t)m * N + nA;
            if (OUT_BF16) { Cb[i0] = f2b(v0); Cb[i0 + 16] = f2b(v1); }
            else { Cf[i0] = v0; Cf[i0 + 16] = v1; }
        }
    }
}

// ---------------- fused align + sparsemax + output ------------------------------
// Block = (2 t-rows, b). scores via sum_d v_d tanh(w+u) = sumv - 2*sum v_d/(E*U+1);
// E/v preloaded to LDS (broadcast ds_read_b128/iter), U bf16 (B,D,S) coalesced.
// Output attn = p @ M2[b] + Y, using compacted sparsemax support lists.
__global__ __launch_bounds__(256) void align5(const float* __restrict__ Ewq,
                                              const ushort* __restrict__ EuT,
                                              const int* __restrict__ mask,
                                              const float* __restrict__ v,
                                              const ushort* __restrict__ M2,
                                              const float* __restrict__ Y,
                                              float* __restrict__ align_out,
                                              float* __restrict__ out0) {
    const int tg = blockIdx.x, b = blockIdx.y;
    const int t0 = tg * 2, t1 = t0 + 1;
    const int bt0 = b * TT + t0, bt1 = bt0 + 1;
    const int tid = threadIdx.x;
    const int lane = tid & 63;
    const int wave = tid >> 6;
    __shared__ float4 EL[DD];       // {E0, E1, v, -} 8 KB
    __shared__ float zs0[SS], zs1[SS];
    __shared__ float svp[4];
    __shared__ float4 cmb[2][128];  // output partial combine
    __shared__ int lst0[SS], lst1[SS];
    __shared__ int cnt[2];

    if (tid < 2) cnt[tid] = 0;
    // preload EL + sum(v)
    const float* E0p = Ewq + (size_t)bt0 * DD;
    const float* E1p = Ewq + (size_t)bt1 * DD;
    float pv = 0.f;
    for (int d = tid; d < DD; d += 256) {
        float vv = v[d];
        EL[d] = make_float4(E0p[d], E1p[d], vv, 0.f);
        pv += vv;
    }
#pragma unroll
    for (int off = 32; off > 0; off >>= 1) pv += __shfl_xor(pv, off, 64);
    if (lane == 0) svp[wave] = pv;
    __syncthreads();
    const float sv = svp[0] + svp[1] + svp[2] + svp[3];

    // scores: thread owns s = tid
    const ushort* U = EuT + (size_t)b * DD * SS + tid;
    float a0 = 0.f, a1 = 0.f;
#pragma unroll 16
    for (int d = 0; d < DD; ++d) {
        float u = b2f(U[(size_t)d * SS]);
        float4 el = EL[d];
        float den0 = __builtin_fmaf(el.x, u, 1.0f);
        float den1 = __builtin_fmaf(el.y, u, 1.0f);
        a0 = __builtin_fmaf(el.z, __builtin_amdgcn_rcpf(den0), a0);
        a1 = __builtin_fmaf(el.z, __builtin_amdgcn_rcpf(den1), a1);
    }
    int mk = mask[b * SS + tid];
    zs0[tid] = mk ? (sv - 2.0f * a0) : -1e9f;
    zs1[tid] = mk ? (sv - 2.0f * a1) : -1e9f;
    __syncthreads();

    // sparsemax: wave 0 -> zs0, wave 1 -> zs1 (shuffle-only)
    if (wave < 2) {
        float* zz = wave ? zs1 : zs0;
        float z0 = zz[lane];
        float z1 = zz[lane + 64];
        float z2 = zz[lane + 128];
        float z3 = zz[lane + 192];
        float mx = fmaxf(fmaxf(z0, z1), fmaxf(z2, z3));
#pragma unroll
        for (int off = 32; off > 0; off >>= 1) mx = fmaxf(mx, __shfl_xor(mx, off, 64));
        z0 -= mx; z1 -= mx; z2 -= mx; z3 -= mx;
        float lo = -1.0f, hi = 0.0f;
        for (int it = 0; it < 24; ++it) {
            float mid = 0.5f * (lo + hi);
            float ssum = fmaxf(z0 - mid, 0.f) + fmaxf(z1 - mid, 0.f) +
                         fmaxf(z2 - mid, 0.f) + fmaxf(z3 - mid, 0.f);
#pragma unroll
            for (int off = 32; off > 0; off >>= 1) ssum += __shfl_xor(ssum, off, 64);
            if (ssum >= 1.0f) lo = mid; else hi = mid;
        }
        float tau = 0.5f * (lo + hi);
        zz[lane] = fmaxf(z0 - tau, 0.f);
        zz[lane + 64] = fmaxf(z1 - tau, 0.f);
        zz[lane + 128] = fmaxf(z2 - tau, 0.f);
        zz[lane + 192] = fmaxf(z3 - tau, 0.f);
    }
    __syncthreads();

    align_out[((size_t)t0 * BB + b) * SS + tid] = zs0[tid];
    align_out[((size_t)t1 * BB + b) * SS + tid] = zs1[tid];

    // compact support lists (order-free; sum commutes)
    if (zs0[tid] > 0.f) lst0[atomicAdd(&cnt[0], 1)] = tid;
    if (zs1[tid] > 0.f) lst1[atomicAdd(&cnt[1], 1)] = tid;
    __syncthreads();
    const int n0c = cnt[0], n1c = cnt[1];

    // out rows: thread ch = tid&127 owns d = ch*4..+3 for BOTH t; sg splits list
    const int ch = tid & 127, sg = tid >> 7;
    const ushort* M2b = M2 + (size_t)b * SS * DD + ch * 4;
    float4 at0 = {0.f, 0.f, 0.f, 0.f}, at1 = {0.f, 0.f, 0.f, 0.f};
#pragma unroll 4
    for (int j = sg; j < n0c; j += 2) {
        int s = lst0[j];
        float p = zs0[s];
        ushort4 m4 = *(const ushort4*)(M2b + (size_t)s * DD);
        at0.x = __builtin_fmaf(p, b2f(m4.x), at0.x);
        at0.y = __builtin_fmaf(p, b2f(m4.y), at0.y);
        at0.z = __builtin_fmaf(p, b2f(m4.z), at0.z);
        at0.w = __builtin_fmaf(p, b2f(m4.w), at0.w);
    }
#pragma unroll 4
    for (int j = sg; j < n1c; j += 2) {
        int s = lst1[j];
        float p = zs1[s];
        ushort4 m4 = *(const ushort4*)(M2b + (size_t)s * DD);
        at1.x = __builtin_fmaf(p, b2f(m4.x), at1.x);
        at1.y = __builtin_fmaf(p, b2f(m4.y), at1.y);
        at1.z = __builtin_fmaf(p, b2f(m4.z), at1.z);
        at1.w = __builtin_fmaf(p, b2f(m4.w), at1.w);
    }
    if (sg == 1) { cmb[0][ch] = at0; cmb[1][ch] = at1; }
    __syncthreads();
    if (sg == 0) {
        float4 p0 = cmb[0][ch], p1 = cmb[1][ch];
        const float4* Y0 = (const float4*)(Y + (size_t)bt0 * DD);
        const float4* Y1 = (const float4*)(Y + (size_t)bt1 * DD);
        float4 y0 = Y0[ch], y1 = Y1[ch];
        float4 o0, o1;
        o0.x = at0.x + p0.x + y0.x; o0.y = at0.y + p0.y + y0.y;
        o0.z = at0.z + p0.z + y0.z; o0.w = at0.w + p0.w + y0.w;
        o1.x = at1.x + p1.x + y1.x; o1.y = at1.y + p1.y + y1.y;
        o1.z = at1.z + p1.z + y1.z; o1.w = at1.w + p1.w + y1.w;
        float4* O0 = (float4*)(out0 + ((size_t)t0 * BB + b) * DD);
        float4* O1 = (float4*)(out0 + ((size_t)t1 * BB + b) * DD);
        O0[ch] = o0;
        O1[ch] = o1;
    }
}

extern "C" void kernel_launch(void* const* d_in, const int* in_sizes, int n_in,
                              void* d_out, int out_size, void* d_ws, size_t ws_size,
                              hipStream_t stream) {
    const float* source = (const float*)d_in[0];       // (B,T,D)
    const float* memory_bank = (const float*)d_in[1];  // (B,S,D)
    const int* memory_mask = (const int*)d_in[2];      // (B,S)
    const float* W_q = (const float*)d_in[3];          // (D,D)
    const float* b_q = (const float*)d_in[4];          // (D,)
    const float* W_c = (const float*)d_in[5];          // (D,D)
    const float* v = (const float*)d_in[6];            // (D,)
    const float* W_out = (const float*)d_in[7];        // (D,2D)
    const float* b_out = (const float*)d_in[8];        // (D,)

    float* out0 = (float*)d_out;                   // attn_h (T,B,D)
    float* out1 = out0 + (size_t)TT * BB * DD;     // align_vectors (T,B,S)

    // workspace (~19.3 MB)
    float* Ewq = (float*)d_ws;                     // (B*T, D) fp32 exp(2wq)  2 MB
    float* Y = Ewq + S_SRC;                        // (B*T, D) fp32 src@Wo2^T+b 2 MB
    ushort* EuT = (ushort*)(Y + S_SRC);            // (B, D, S) bf16 exp(2uh) 4 MB
    ushort* M2 = EuT + S_MB;                       // (B, S, D) bf16 mb@Wo1^T 4 MB
    ushort* src_b = M2 + S_MB;                     // 1 MB
    ushort* mb_b = src_b + S_SRC;                  // 4 MB
    ushort* wqw_b = mb_b + S_MB;                   // 0.5 MB
    ushort* wcw_b = wqw_b + S_WQ;                  // 0.5 MB
    ushort* wo_b = wcw_b + S_WC;                   // 1 MB

    dim3 blk(256);
    // 1. cast bf16 operands
    int ngroups = (S_SRC + S_MB + S_WQ + S_WC + S_WO) / 4;
    cast_all<<<dim3(ngroups / 256), blk, 0, stream>>>(
        source, memory_bank, W_q, W_c, W_out, src_b, mb_b, wqw_b, wcw_b, wo_b);
    // 2. Ewq = exp(2*(source @ W_q^T + b_q))        M=1024 N=512 K=512
    gemm_lds<1, 1, 0, 0><<<dim3(8, 16), blk, 0, stream>>>(
        src_b, wqw_b, b_q, Ewq, BB * TT, DD, DD, DD, DD);
    // 3. EuT[b] = exp(2*(W_c @ mb[b]^T)) bf16       M=512(d) N=256(s) K=512, batch 16
    gemm_lds<0, 1, 1, 2><<<dim3(4, 8, BB), blk, 0, stream>>>(
        wcw_b, mb_b, nullptr, EuT, DD, SS, DD, DD, DD);
    // 4. M2[b] = mb[b] @ Wo1^T bf16                 M=256(s) N=512(d) K=512, batch 16
    gemm_lds<0, 0, 1, 1><<<dim3(8, 4, BB), blk, 0, stream>>>(
        mb_b, wo_b, nullptr, M2, SS, DD, DD, DD, 2 * DD);
    // 5. Y = source @ Wo2^T + b_out                 M=1024 N=512 K=512
    gemm_lds<1, 0, 0, 0><<<dim3(8, 16), blk, 0, stream>>>(
        src_b, wo_b + DD, b_out, Y, BB * TT, DD, DD, DD, 2 * DD);
    // 6. fused align + sparsemax + output
    align5<<<dim3(TT / 2, BB), blk, 0, stream>>>(
        Ewq, EuT, memory_mask, v, M2, Y, out1, out0);
}

// Round 6
// 125.734 us; speedup vs baseline: 1.5948x; 1.0982x over previous
//
#include <hip/hip_runtime.h>
#include <hip/hip_bf16.h>

#define BB 16
#define TT 64
#define SS 256
#define DD 512

typedef __bf16 bf16x8 __attribute__((ext_vector_type(8)));
typedef float f32x4 __attribute__((ext_vector_type(4)));

__device__ __forceinline__ ushort f2b(float x) {
    __hip_bfloat16 h = __float2bfloat16(x);
    return __builtin_bit_cast(ushort, h);
}
__device__ __forceinline__ float b2f(ushort u) {
    unsigned int x = (unsigned int)u << 16;
    return __builtin_bit_cast(float, x);
}

// ---------------- fp32 -> bf16 cast of the 5 GEMM operands, one launch ----------
#define S_SRC (BB * TT * DD)   // 524288
#define S_MB  (BB * SS * DD)   // 2097152
#define S_WQ  (DD * DD)        // 262144
#define S_WC  (DD * DD)        // 262144
#define S_WO  (DD * 2 * DD)    // 524288

__global__ __launch_bounds__(256) void cast_all(
    const float* __restrict__ src, const float* __restrict__ mb,
    const float* __restrict__ wq, const float* __restrict__ wc,
    const float* __restrict__ wo,
    ushort* __restrict__ src_b, ushort* __restrict__ mb_b,
    ushort* __restrict__ wq_b, ushort* __restrict__ wc_b,
    ushort* __restrict__ wo_b) {
    int g = blockIdx.x * 256 + threadIdx.x;  // float4-group index
    const int G0 = S_SRC / 4, G1 = S_MB / 4, G2 = S_WQ / 4, G3 = S_WC / 4;
    const float* in;
    ushort* out;
    int local;
    if (g < G0) { in = src; out = src_b; local = g; }
    else if (g < G0 + G1) { in = mb; out = mb_b; local = g - G0; }
    else if (g < G0 + G1 + G2) { in = wq; out = wq_b; local = g - G0 - G1; }
    else if (g < G0 + G1 + G2 + G3) { in = wc; out = wc_b; local = g - G0 - G1 - G2; }
    else { in = wo; out = wo_b; local = g - G0 - G1 - G2 - G3; }
    float4 x = *(const float4*)(in + (size_t)local * 4);
    ushort4 y = {f2b(x.x), f2b(x.y), f2b(x.z), f2b(x.w)};
    *(ushort4*)(out + (size_t)local * 4) = y;
}

// ---------------- mega-GEMM: all 4 independent GEMMs in one flat grid ----------
// 64x64 tile, BK=64, K=512 (8 phases), lda=512 for every mode.
// Flat block id -> mode:
//   [0,128)    mode0: Ewq = exp(2*(src @ W_q^T + b_q))      fp32 (1024x512)
//   [128,256)  mode1: Y   = src @ Wo2^T + b_out             fp32 (1024x512)
//   [256,768)  mode2: EuT[b] = exp(2*(W_c @ mb[b]^T))       bf16 (512x256), batch 16
//   [768,1280) mode3: M2[b]  = mb[b] @ Wo1^T                bf16 (256x512), batch 16
__global__ __launch_bounds__(256) void mega_gemm(
    const ushort* __restrict__ src_b, const ushort* __restrict__ mb_b,
    const ushort* __restrict__ wqw_b, const ushort* __restrict__ wcw_b,
    const ushort* __restrict__ wo_b,
    const float* __restrict__ b_q, const float* __restrict__ b_out,
    float* __restrict__ Ewq, float* __restrict__ Y,
    ushort* __restrict__ EuT, ushort* __restrict__ M2) {
    __shared__ ushort Asm[64 * 72];
    __shared__ ushort Bsm[64 * 72];
    const int id = blockIdx.x;
    const ushort* Ab;
    const ushort* Bb;
    const float* bias = nullptr;
    void* Cp;
    int ldb, N, m0, n0;
    bool exp2x, obf16, hasb;
    size_t coff = 0;
    if (id < 256) {
        const bool isY = id >= 128;
        const int l = id & 127;
        m0 = (l >> 3) * 64; n0 = (l & 7) * 64;
        Ab = src_b;
        Bb = isY ? (wo_b + DD) : wqw_b;
        ldb = isY ? 2 * DD : DD;
        bias = isY ? b_out : b_q;
        hasb = true; exp2x = !isY; obf16 = false; N = DD;
        Cp = isY ? (void*)Y : (void*)Ewq;
    } else if (id < 768) {
        const int l = id - 256;
        const int bz = l >> 5, tl = l & 31;   // 8 (d) x 4 (s) tiles
        m0 = (tl >> 2) * 64; n0 = (tl & 3) * 64;
        Ab = wcw_b;
        Bb = mb_b + (size_t)bz * SS * DD;
        ldb = DD;
        hasb = false; exp2x = true; obf16 = true; N = SS;
        Cp = (void*)EuT; coff = (size_t)bz * DD * SS;
    } else {
        const int l = id - 768;
        const int bz = l >> 5, tl = l & 31;   // 4 (s) x 8 (d) tiles
        m0 = (tl >> 3) * 64; n0 = (tl & 7) * 64;
        Ab = mb_b + (size_t)bz * SS * DD;
        Bb = wo_b;
        ldb = 2 * DD;
        hasb = false; exp2x = false; obf16 = true; N = DD;
        Cp = (void*)M2; coff = (size_t)bz * SS * DD;
    }

    const int tid = threadIdx.x;
    const int lane = tid & 63;
    const int wave = tid >> 6;
    const int wm = wave & 1, wn = wave >> 1;

    const int srow = tid >> 3;    // 0..31
    const int schunk = tid & 7;   // 8-bf16 chunk within the 64-k slice
    const ushort* Ag0 = Ab + (size_t)(m0 + srow) * DD + schunk * 8;
    const ushort* Ag1 = Ag0 + (size_t)32 * DD;
    const ushort* Bg0 = Bb + (size_t)(n0 + srow) * ldb + schunk * 8;
    const ushort* Bg1 = Bg0 + (size_t)32 * ldb;
    const int lw = srow * 72 + schunk * 8;

    const int l15 = lane & 15, quad = lane >> 4;
    const int ar = (wm * 32 + l15) * 72 + quad * 8;
    const int br = (wn * 32 + l15) * 72 + quad * 8;

    f32x4 acc00 = {0.f, 0.f, 0.f, 0.f}, acc01 = {0.f, 0.f, 0.f, 0.f};
    f32x4 acc10 = {0.f, 0.f, 0.f, 0.f}, acc11 = {0.f, 0.f, 0.f, 0.f};

    uint4 a0 = *(const uint4*)Ag0;
    uint4 a1 = *(const uint4*)Ag1;
    uint4 b0 = *(const uint4*)Bg0;
    uint4 b1 = *(const uint4*)Bg1;
    const int P = DD >> 6;  // 8 phases
    for (int p = 0; p < P; ++p) {
        __syncthreads();  // prior phase's ds_reads complete
        *(uint4*)&Asm[lw] = a0;
        *(uint4*)&Asm[lw + 32 * 72] = a1;
        *(uint4*)&Bsm[lw] = b0;
        *(uint4*)&Bsm[lw + 32 * 72] = b1;
        __syncthreads();
        if (p + 1 < P) {  // prefetch next slice, overlaps compute below
            int ko = (p + 1) << 6;
            a0 = *(const uint4*)(Ag0 + ko);
            a1 = *(const uint4*)(Ag1 + ko);
            b0 = *(const uint4*)(Bg0 + ko);
            b1 = *(const uint4*)(Bg1 + ko);
        }
        bf16x8 fa0 = *(const bf16x8*)&Asm[ar];
        bf16x8 fa1 = *(const bf16x8*)&Asm[ar + 16 * 72];
        bf16x8 fb0 = *(const bf16x8*)&Bsm[br];
        bf16x8 fb1 = *(const bf16x8*)&Bsm[br + 16 * 72];
        acc00 = __builtin_amdgcn_mfma_f32_16x16x32_bf16(fa0, fb0, acc00, 0, 0, 0);
        acc01 = __builtin_amdgcn_mfma_f32_16x16x32_bf16(fa0, fb1, acc01, 0, 0, 0);
        acc10 = __builtin_amdgcn_mfma_f32_16x16x32_bf16(fa1, fb0, acc10, 0, 0, 0);
        acc11 = __builtin_amdgcn_mfma_f32_16x16x32_bf16(fa1, fb1, acc11, 0, 0, 0);
        fa0 = *(const bf16x8*)&Asm[ar + 32];
        fa1 = *(const bf16x8*)&Asm[ar + 16 * 72 + 32];
        fb0 = *(const bf16x8*)&Bsm[br + 32];
        fb1 = *(const bf16x8*)&Bsm[br + 16 * 72 + 32];
        acc00 = __builtin_amdgcn_mfma_f32_16x16x32_bf16(fa0, fb0, acc00, 0, 0, 0);
        acc01 = __builtin_amdgcn_mfma_f32_16x16x32_bf16(fa0, fb1, acc01, 0, 0, 0);
        acc10 = __builtin_amdgcn_mfma_f32_16x16x32_bf16(fa1, fb0, acc10, 0, 0, 0);
        acc11 = __builtin_amdgcn_mfma_f32_16x16x32_bf16(fa1, fb1, acc11, 0, 0, 0);
    }
    // epilogue: C/D layout col=l15, row=quad*4+reg
    const int nA = n0 + wn * 32 + l15;
    float bias0 = 0.f, bias1 = 0.f;
    if (hasb) { bias0 = bias[nA]; bias1 = bias[nA + 16]; }
    float* Cf = (float*)Cp;
    ushort* Cb = (ushort*)Cp;
#pragma unroll
    for (int mt = 0; mt < 2; ++mt) {
        f32x4 accN0 = mt ? acc10 : acc00;
        f32x4 accN1 = mt ? acc11 : acc01;
#pragma unroll
        for (int r = 0; r < 4; ++r) {
            int m = m0 + wm * 32 + mt * 16 + quad * 4 + r;
            float v0 = accN0[r] + bias0;
            float v1 = accN1[r] + bias1;
            if (exp2x) { v0 = __expf(2.0f * v0); v1 = __expf(2.0f * v1); }
            size_t i0 = coff + (size_t)m * N + nA;
            if (obf16) { Cb[i0] = f2b(v0); Cb[i0 + 16] = f2b(v1); }
            else { Cf[i0] = v0; Cf[i0 + 16] = v1; }
        }
    }
}

// ---------------- fused align + sparsemax + output ------------------------------
// Block = (2 t-rows, b). scores via sum_d v_d tanh(w+u) = sumv - 2*sum v_d/(E*U+1);
// E/v preloaded to LDS (broadcast ds_read_b128/iter), U bf16 (B,D,S) coalesced.
// Output attn = p @ M2[b] + Y, using compacted sparsemax support lists.
__global__ __launch_bounds__(256) void align5(const float* __restrict__ Ewq,
                                              const ushort* __restrict__ EuT,
                                              const int* __restrict__ mask,
                                              const float* __restrict__ v,
                                              const ushort* __restrict__ M2,
                                              const float* __restrict__ Y,
                                              float* __restrict__ align_out,
                                              float* __restrict__ out0) {
    const int tg = blockIdx.x, b = blockIdx.y;
    const int t0 = tg * 2, t1 = t0 + 1;
    const int bt0 = b * TT + t0, bt1 = bt0 + 1;
    const int tid = threadIdx.x;
    const int lane = tid & 63;
    const int wave = tid >> 6;
    __shared__ float4 EL[DD];       // {E0, E1, v, -} 8 KB
    __shared__ float zs0[SS], zs1[SS];
    __shared__ float svp[4];
    __shared__ float4 cmb[2][128];  // output partial combine
    __shared__ int lst0[SS], lst1[SS];
    __shared__ int cnt[2];

    if (tid < 2) cnt[tid] = 0;
    // preload EL + sum(v)
    const float* E0p = Ewq + (size_t)bt0 * DD;
    const float* E1p = Ewq + (size_t)bt1 * DD;
    float pv = 0.f;
    for (int d = tid; d < DD; d += 256) {
        float vv = v[d];
        EL[d] = make_float4(E0p[d], E1p[d], vv, 0.f);
        pv += vv;
    }
#pragma unroll
    for (int off = 32; off > 0; off >>= 1) pv += __shfl_xor(pv, off, 64);
    if (lane == 0) svp[wave] = pv;
    __syncthreads();
    const float sv = svp[0] + svp[1] + svp[2] + svp[3];

    // scores: thread owns s = tid
    const ushort* U = EuT + (size_t)b * DD * SS + tid;
    float a0 = 0.f, a1 = 0.f;
#pragma unroll 16
    for (int d = 0; d < DD; ++d) {
        float u = b2f(U[(size_t)d * SS]);
        float4 el = EL[d];
        float den0 = __builtin_fmaf(el.x, u, 1.0f);
        float den1 = __builtin_fmaf(el.y, u, 1.0f);
        a0 = __builtin_fmaf(el.z, __builtin_amdgcn_rcpf(den0), a0);
        a1 = __builtin_fmaf(el.z, __builtin_amdgcn_rcpf(den1), a1);
    }
    int mk = mask[b * SS + tid];
    zs0[tid] = mk ? (sv - 2.0f * a0) : -1e9f;
    zs1[tid] = mk ? (sv - 2.0f * a1) : -1e9f;
    __syncthreads();

    // sparsemax: wave 0 -> zs0, wave 1 -> zs1 (shuffle-only)
    if (wave < 2) {
        float* zz = wave ? zs1 : zs0;
        float z0 = zz[lane];
        float z1 = zz[lane + 64];
        float z2 = zz[lane + 128];
        float z3 = zz[lane + 192];
        float mx = fmaxf(fmaxf(z0, z1), fmaxf(z2, z3));
#pragma unroll
        for (int off = 32; off > 0; off >>= 1) mx = fmaxf(mx, __shfl_xor(mx, off, 64));
        z0 -= mx; z1 -= mx; z2 -= mx; z3 -= mx;
        float lo = -1.0f, hi = 0.0f;
        for (int it = 0; it < 24; ++it) {
            float mid = 0.5f * (lo + hi);
            float ssum = fmaxf(z0 - mid, 0.f) + fmaxf(z1 - mid, 0.f) +
                         fmaxf(z2 - mid, 0.f) + fmaxf(z3 - mid, 0.f);
#pragma unroll
            for (int off = 32; off > 0; off >>= 1) ssum += __shfl_xor(ssum, off, 64);
            if (ssum >= 1.0f) lo = mid; else hi = mid;
        }
        float tau = 0.5f * (lo + hi);
        zz[lane] = fmaxf(z0 - tau, 0.f);
        zz[lane + 64] = fmaxf(z1 - tau, 0.f);
        zz[lane + 128] = fmaxf(z2 - tau, 0.f);
        zz[lane + 192] = fmaxf(z3 - tau, 0.f);
    }
    __syncthreads();

    align_out[((size_t)t0 * BB + b) * SS + tid] = zs0[tid];
    align_out[((size_t)t1 * BB + b) * SS + tid] = zs1[tid];

    // compact support lists (order-free; sum commutes)
    if (zs0[tid] > 0.f) lst0[atomicAdd(&cnt[0], 1)] = tid;
    if (zs1[tid] > 0.f) lst1[atomicAdd(&cnt[1], 1)] = tid;
    __syncthreads();
    const int n0c = cnt[0], n1c = cnt[1];

    // out rows: thread ch = tid&127 owns d = ch*4..+3 for BOTH t; sg splits list
    const int ch = tid & 127, sg = tid >> 7;
    const ushort* M2b = M2 + (size_t)b * SS * DD + ch * 4;
    float4 at0 = {0.f, 0.f, 0.f, 0.f}, at1 = {0.f, 0.f, 0.f, 0.f};
#pragma unroll 4
    for (int j = sg; j < n0c; j += 2) {
        int s = lst0[j];
        float p = zs0[s];
        ushort4 m4 = *(const ushort4*)(M2b + (size_t)s * DD);
        at0.x = __builtin_fmaf(p, b2f(m4.x), at0.x);
        at0.y = __builtin_fmaf(p, b2f(m4.y), at0.y);
        at0.z = __builtin_fmaf(p, b2f(m4.z), at0.z);
        at0.w = __builtin_fmaf(p, b2f(m4.w), at0.w);
    }
#pragma unroll 4
    for (int j = sg; j < n1c; j += 2) {
        int s = lst1[j];
        float p = zs1[s];
        ushort4 m4 = *(const ushort4*)(M2b + (size_t)s * DD);
        at1.x = __builtin_fmaf(p, b2f(m4.x), at1.x);
        at1.y = __builtin_fmaf(p, b2f(m4.y), at1.y);
        at1.z = __builtin_fmaf(p, b2f(m4.z), at1.z);
        at1.w = __builtin_fmaf(p, b2f(m4.w), at1.w);
    }
    if (sg == 1) { cmb[0][ch] = at0; cmb[1][ch] = at1; }
    __syncthreads();
    if (sg == 0) {
        float4 p0 = cmb[0][ch], p1 = cmb[1][ch];
        const float4* Y0 = (const float4*)(Y + (size_t)bt0 * DD);
        const float4* Y1 = (const float4*)(Y + (size_t)bt1 * DD);
        float4 y0 = Y0[ch], y1 = Y1[ch];
        float4 o0, o1;
        o0.x = at0.x + p0.x + y0.x; o0.y = at0.y + p0.y + y0.y;
        o0.z = at0.z + p0.z + y0.z; o0.w = at0.w + p0.w + y0.w;
        o1.x = at1.x + p1.x + y1.x; o1.y = at1.y + p1.y + y1.y;
        o1.z = at1.z + p1.z + y1.z; o1.w = at1.w + p1.w + y1.w;
        float4* O0 = (float4*)(out0 + ((size_t)t0 * BB + b) * DD);
        float4* O1 = (float4*)(out0 + ((size_t)t1 * BB + b) * DD);
        O0[ch] = o0;
        O1[ch] = o1;
    }
}

extern "C" void kernel_launch(void* const* d_in, const int* in_sizes, int n_in,
                              void* d_out, int out_size, void* d_ws, size_t ws_size,
                              hipStream_t stream) {
    const float* source = (const float*)d_in[0];       // (B,T,D)
    const float* memory_bank = (const float*)d_in[1];  // (B,S,D)
    const int* memory_mask = (const int*)d_in[2];      // (B,S)
    const float* W_q = (const float*)d_in[3];          // (D,D)
    const float* b_q = (const float*)d_in[4];          // (D,)
    const float* W_c = (const float*)d_in[5];          // (D,D)
    const float* v = (const float*)d_in[6];            // (D,)
    const float* W_out = (const float*)d_in[7];        // (D,2D)
    const float* b_out = (const float*)d_in[8];        // (D,)

    float* out0 = (float*)d_out;                   // attn_h (T,B,D)
    float* out1 = out0 + (size_t)TT * BB * DD;     // align_vectors (T,B,S)

    // workspace (~19.3 MB)
    float* Ewq = (float*)d_ws;                     // (B*T, D) fp32 exp(2wq)  2 MB
    float* Y = Ewq + S_SRC;                        // (B*T, D) fp32 src@Wo2^T+b 2 MB
    ushort* EuT = (ushort*)(Y + S_SRC);            // (B, D, S) bf16 exp(2uh) 4 MB
    ushort* M2 = EuT + S_MB;                       // (B, S, D) bf16 mb@Wo1^T 4 MB
    ushort* src_b = M2 + S_MB;                     // 1 MB
    ushort* mb_b = src_b + S_SRC;                  // 4 MB
    ushort* wqw_b = mb_b + S_MB;                   // 0.5 MB
    ushort* wcw_b = wqw_b + S_WQ;                  // 0.5 MB
    ushort* wo_b = wcw_b + S_WC;                   // 1 MB

    dim3 blk(256);
    // 1. cast bf16 operands
    int ngroups = (S_SRC + S_MB + S_WQ + S_WC + S_WO) / 4;
    cast_all<<<dim3(ngroups / 256), blk, 0, stream>>>(
        source, memory_bank, W_q, W_c, W_out, src_b, mb_b, wqw_b, wcw_b, wo_b);
    // 2. all four GEMMs, one dispatch (1280 blocks ~ 5/CU)
    mega_gemm<<<dim3(1280), blk, 0, stream>>>(
        src_b, mb_b, wqw_b, wcw_b, wo_b, b_q, b_out, Ewq, Y, EuT, M2);
    // 3. fused align + sparsemax + output
    align5<<<dim3(TT / 2, BB), blk, 0, stream>>>(
        Ewq, EuT, memory_mask, v, M2, Y, out1, out0);
}